// Round 18
// baseline (292.901 us; speedup 1.0000x reference)
//
#include <hip/hip_runtime.h>
#include <stdint.h>

#define NN 50000
#define EE 600000
#define DD 128
#define LL 3
#define NB 196    // ceil(NN/256)
#define NBKT 196  // buckets of 256 nodes
#define NBANK 16
#define SB (NBANK * 256)  // floats per banked stats stage
#define GA 3125           // gather blocks: 16 nodes/block, GA*16 == NN exactly
#define B1CH 2048         // stage-1 chunk (edges per block)
#define B1G ((EE + B1CH - 1) / B1CH)

typedef __attribute__((ext_vector_type(8))) short short8;
typedef __attribute__((ext_vector_type(4))) float f32x4;
typedef __attribute__((ext_vector_type(4))) unsigned int u32x4;

static __device__ __forceinline__ ushort f2bf(float f) {
    uint32_t u = __builtin_bit_cast(uint32_t, f);
    u += 0x7FFFu + ((u >> 16) & 1u);
    return (ushort)(u >> 16);
}
static __device__ __forceinline__ float bf2f(ushort u) {
    uint32_t x = ((uint32_t)u) << 16;
    return __builtin_bit_cast(float, x);
}
static __device__ __forceinline__ float bflo(uint32_t p) { return bf2f((ushort)(p & 0xffffu)); }
static __device__ __forceinline__ float bfhi(uint32_t p) { return bf2f((ushort)(p >> 16)); }

static __device__ __forceinline__ void gload_lds16(const void* g, void* l) {
    __builtin_amdgcn_global_load_lds(
        (const __attribute__((address_space(1))) uint32_t*)g,
        (__attribute__((address_space(3))) uint32_t*)l, 16, 0, 0);
}

static __device__ __forceinline__ float2 bank_sum(const float* st, int t) {
    float s1 = 0.f, s2 = 0.f;
    #pragma unroll
    for (int bb = 0; bb < NBANK; ++bb) {
        s1 += st[bb * 256 + t];
        s2 += st[bb * 256 + DD + t];
    }
    return make_float2(s1, s2);
}

// ------- prep: W -> W^T bf16 slot-swizzled (blocks 0..11) + zero deg/stats -------
__global__ __launch_bounds__(256) void prep_w(
    const float* __restrict__ W0s, const float* __restrict__ W1s,
    ushort* __restrict__ wt, int* __restrict__ deg, float* __restrict__ stats)
{
    __shared__ float ws[8192];
    const int b = blockIdx.x;
    const int t = threadIdx.x;

    {
        int i = b * 256 + t;
        if (i < NN) deg[i] = 0;
        if (b >= 12 && b < 12 + 9 * NBANK) stats[(b - 12) * 256 + t] = 0.f;
    }

    if (b < 12) {
        const int m = b >> 1, kh = b & 1;
        const float* W = (m < 3 ? W0s + (size_t)m * 16384
                                : W1s + (size_t)(m - 3) * 16384) + (size_t)kh * 64 * 128;
        #pragma unroll
        for (int i = 0; i < 8; ++i) {
            int i4 = t + i * 256;
            reinterpret_cast<float4*>(ws)[i4] = reinterpret_cast<const float4*>(W)[i4];
        }
        __syncthreads();
        ushort* out = wt + (size_t)m * 16384;
        const int j = t & 127;
        const int rep = t >> 7;
        #pragma unroll
        for (int si = 0; si < 4; ++si) {
            int s = kh * 8 + rep * 4 + si;
            int kloc = (rep * 4 + si) * 8;
            short8 pk;
            #pragma unroll
            for (int q = 0; q < 8; ++q) pk[q] = (short)f2bf(ws[(kloc + q) * 128 + j]);
            int slot = s ^ (j & 7);
            *reinterpret_cast<short8*>(out + j * 128 + slot * 8) = pk;
        }
    }
}

// ---------------- CSR build ----------------
__global__ __launch_bounds__(256) void hist_kernel(
    const int* __restrict__ dst, int* __restrict__ deg)
{
    int e = blockIdx.x * 256 + threadIdx.x;
    if (e < EE) atomicAdd(&deg[dst[e]], 1);
}

__global__ __launch_bounds__(256) void scan_a(
    const int* __restrict__ deg, int* __restrict__ partials)
{
    int i = blockIdx.x * 256 + threadIdx.x;
    int v = (i < NN) ? deg[i] : 0;
    #pragma unroll
    for (int d = 1; d < 64; d <<= 1) v += __shfl_xor(v, d);
    __shared__ int wsum[4];
    if ((threadIdx.x & 63) == 0) wsum[threadIdx.x >> 6] = v;
    __syncthreads();
    if (threadIdx.x == 0)
        partials[blockIdx.x] = wsum[0] + wsum[1] + wsum[2] + wsum[3];
}

__global__ __launch_bounds__(256) void scan_c(
    const int* __restrict__ deg, const int* __restrict__ partials,
    int* __restrict__ off, int* __restrict__ bcur)
{
    __shared__ int ps[256], s[256];
    const int t = threadIdx.x;
    int pv = (t < NB) ? partials[t] : 0;
    ps[t] = pv;
    __syncthreads();
    for (int d = 1; d < 256; d <<= 1) {
        int u = (t >= d) ? ps[t - d] : 0;
        __syncthreads();
        ps[t] += u;
        __syncthreads();
    }
    int base = (blockIdx.x > 0) ? ps[blockIdx.x - 1] : 0;

    int i = blockIdx.x * 256 + t;
    int v = (i < NN) ? deg[i] : 0;
    s[t] = v;
    __syncthreads();
    for (int d = 1; d < 256; d <<= 1) {
        int u = (t >= d) ? s[t - d] : 0;
        __syncthreads();
        s[t] += u;
        __syncthreads();
    }
    int excl = base + s[t] - v;
    if (i < NN) {
        off[i] = excl;
        if ((i & 255) == 0) bcur[i >> 8] = excl;
    }
    if (i == 0) off[NN] = EE;
}

// ------- binsort stage 1: chunk-local count -> reserve -> place into staging -------
__global__ __launch_bounds__(256) void bin_stage1(
    const int* __restrict__ src, const int* __restrict__ dst,
    const float* __restrict__ w, int* __restrict__ bcur,
    int2* __restrict__ stg)
{
    __shared__ int cnt[NBKT], gb[NBKT];
    const int t = threadIdx.x;
    const int e0 = blockIdx.x * B1CH;
    for (int b = t; b < NBKT; b += 256) cnt[b] = 0;
    __syncthreads();
    #pragma unroll
    for (int k = 0; k < B1CH / 256; ++k) {
        int e = e0 + k * 256 + t;
        if (e < EE) atomicAdd(&cnt[dst[e] >> 8], 1);
    }
    __syncthreads();
    for (int b = t; b < NBKT; b += 256) {
        int c = cnt[b];
        if (c > 0) gb[b] = atomicAdd(&bcur[b], c);
        cnt[b] = 0;
    }
    __syncthreads();
    #pragma unroll
    for (int k = 0; k < B1CH / 256; ++k) {
        int e = e0 + k * 256 + t;
        if (e < EE) {
            int d = dst[e];
            int b = d >> 8;
            int p = gb[b] + atomicAdd(&cnt[b], 1);
            stg[p] = make_int2((d << 16) | src[e], __float_as_int(w[e]));
        }
    }
}

// ------- binsort stage 2: per-bucket scatter into final em (XCD-local) -------
__global__ __launch_bounds__(256) void bin_stage2(
    const int* __restrict__ off, const int2* __restrict__ stg,
    int2* __restrict__ em)
{
    __shared__ int lcur[256];
    const int t = threadIdx.x;
    const int b = blockIdx.x;
    const int n0 = b * 256;
    int nidx = n0 + t;
    lcur[t] = (nidx < NN) ? off[nidx] : EE;
    int hi = n0 + 256; if (hi > NN) hi = NN;
    const int rbeg = off[n0];
    const int rend = off[hi];
    __syncthreads();
    for (int p = rbeg + t; p < rend; p += 256) {
        int2 en = stg[p];
        uint32_t key = (uint32_t)en.x;
        int d_local = (int)(key >> 16) & 255;
        int srcv = (int)(key & 0xffffu);
        int pos = atomicAdd(&lcur[d_local], 1);
        em[pos] = make_int2(srcv, en.y);
    }
}

// ------- gather + fused BN1 stats (shuffle-reduced): y[v]=y0[v]+sum w*y0[src] -------
__global__ __launch_bounds__(256) void gather_kernel(
    const ushort* __restrict__ y0, const int* __restrict__ off,
    const long long* __restrict__ em, ushort* __restrict__ y,
    float* __restrict__ st0)
{
    __shared__ float red[4][256];
    const int t = threadIdx.x;
    const int wave = t >> 6, lane = t & 63;
    const int qw = lane >> 4, ql = lane & 15;
    const int v = blockIdx.x * 16 + wave * 4 + qw;

    const int beg = off[v], end = off[v + 1];
    const ushort* rowbase = y0 + ql * 8;

    uint4 sw = *reinterpret_cast<const uint4*>(y0 + (size_t)v * DD + ql * 8);
    float a0 = bflo(sw.x), a1 = bfhi(sw.x), a2 = bflo(sw.y), a3 = bfhi(sw.y);
    float a4 = bflo(sw.z), a5 = bfhi(sw.z), a6 = bflo(sw.w), a7 = bfhi(sw.w);

    int j = beg;
    for (; j + 3 < end; j += 4) {
        long long q0 = __builtin_nontemporal_load(&em[j]);
        long long q1 = __builtin_nontemporal_load(&em[j + 1]);
        long long q2 = __builtin_nontemporal_load(&em[j + 2]);
        long long q3 = __builtin_nontemporal_load(&em[j + 3]);
        int s0 = (int)(q0 & 0xffffffffLL), s1 = (int)(q1 & 0xffffffffLL);
        int s2 = (int)(q2 & 0xffffffffLL), s3 = (int)(q3 & 0xffffffffLL);
        float w0 = __int_as_float((int)(q0 >> 32)), w1 = __int_as_float((int)(q1 >> 32));
        float w2 = __int_as_float((int)(q2 >> 32)), w3 = __int_as_float((int)(q3 >> 32));
        uint4 p0 = *reinterpret_cast<const uint4*>(rowbase + (size_t)s0 * DD);
        uint4 p1 = *reinterpret_cast<const uint4*>(rowbase + (size_t)s1 * DD);
        uint4 p2 = *reinterpret_cast<const uint4*>(rowbase + (size_t)s2 * DD);
        uint4 p3 = *reinterpret_cast<const uint4*>(rowbase + (size_t)s3 * DD);
        a0 = fmaf(w0, bflo(p0.x), a0); a1 = fmaf(w0, bfhi(p0.x), a1);
        a2 = fmaf(w0, bflo(p0.y), a2); a3 = fmaf(w0, bfhi(p0.y), a3);
        a4 = fmaf(w0, bflo(p0.z), a4); a5 = fmaf(w0, bfhi(p0.z), a5);
        a6 = fmaf(w0, bflo(p0.w), a6); a7 = fmaf(w0, bfhi(p0.w), a7);
        a0 = fmaf(w1, bflo(p1.x), a0); a1 = fmaf(w1, bfhi(p1.x), a1);
        a2 = fmaf(w1, bflo(p1.y), a2); a3 = fmaf(w1, bfhi(p1.y), a3);
        a4 = fmaf(w1, bflo(p1.z), a4); a5 = fmaf(w1, bfhi(p1.z), a5);
        a6 = fmaf(w1, bflo(p1.w), a6); a7 = fmaf(w1, bfhi(p1.w), a7);
        a0 = fmaf(w2, bflo(p2.x), a0); a1 = fmaf(w2, bfhi(p2.x), a1);
        a2 = fmaf(w2, bflo(p2.y), a2); a3 = fmaf(w2, bfhi(p2.y), a3);
        a4 = fmaf(w2, bflo(p2.z), a4); a5 = fmaf(w2, bfhi(p2.z), a5);
        a6 = fmaf(w2, bflo(p2.w), a6); a7 = fmaf(w2, bfhi(p2.w), a7);
        a0 = fmaf(w3, bflo(p3.x), a0); a1 = fmaf(w3, bfhi(p3.x), a1);
        a2 = fmaf(w3, bflo(p3.y), a2); a3 = fmaf(w3, bfhi(p3.y), a3);
        a4 = fmaf(w3, bflo(p3.z), a4); a5 = fmaf(w3, bfhi(p3.z), a5);
        a6 = fmaf(w3, bflo(p3.w), a6); a7 = fmaf(w3, bfhi(p3.w), a7);
    }
    for (; j < end; ++j) {
        long long q0 = __builtin_nontemporal_load(&em[j]);
        int s0 = (int)(q0 & 0xffffffffLL);
        float w0 = __int_as_float((int)(q0 >> 32));
        uint4 p0 = *reinterpret_cast<const uint4*>(rowbase + (size_t)s0 * DD);
        a0 = fmaf(w0, bflo(p0.x), a0); a1 = fmaf(w0, bfhi(p0.x), a1);
        a2 = fmaf(w0, bflo(p0.y), a2); a3 = fmaf(w0, bfhi(p0.y), a3);
        a4 = fmaf(w0, bflo(p0.z), a4); a5 = fmaf(w0, bfhi(p0.z), a5);
        a6 = fmaf(w0, bflo(p0.w), a6); a7 = fmaf(w0, bfhi(p0.w), a7);
    }
    ushort r0 = f2bf(a0), r1 = f2bf(a1), r2 = f2bf(a2), r3 = f2bf(a3);
    ushort r4 = f2bf(a4), r5 = f2bf(a5), r6 = f2bf(a6), r7 = f2bf(a7);
    u32x4 ow;
    ow.x = (uint32_t)r0 | ((uint32_t)r1 << 16);
    ow.y = (uint32_t)r2 | ((uint32_t)r3 << 16);
    ow.z = (uint32_t)r4 | ((uint32_t)r5 << 16);
    ow.w = (uint32_t)r6 | ((uint32_t)r7 << 16);
    __builtin_nontemporal_store(ow, reinterpret_cast<u32x4*>(y + (size_t)v * DD + ql * 8));

    float b[8], q[8];
    b[0] = bf2f(r0); b[1] = bf2f(r1); b[2] = bf2f(r2); b[3] = bf2f(r3);
    b[4] = bf2f(r4); b[5] = bf2f(r5); b[6] = bf2f(r6); b[7] = bf2f(r7);
    #pragma unroll
    for (int k = 0; k < 8; ++k) {
        q[k] = b[k] * b[k];
        b[k] += __shfl_xor(b[k], 16); q[k] += __shfl_xor(q[k], 16);
        b[k] += __shfl_xor(b[k], 32); q[k] += __shfl_xor(q[k], 32);
    }
    if (qw == 0) {
        #pragma unroll
        for (int k = 0; k < 8; ++k) {
            red[wave][ql * 8 + k] = b[k];
            red[wave][128 + ql * 8 + k] = q[k];
        }
    }
    __syncthreads();
    if (t < 128) {
        float s1 = red[0][t] + red[1][t] + red[2][t] + red[3][t];
        float s2 = red[0][128 + t] + red[1][128 + t] + red[2][128 + t] + red[3][128 + t];
        float* stb = st0 + (blockIdx.x & (NBANK - 1)) * 256;
        atomicAdd(&stb[t], s1);
        atomicAdd(&stb[DD + t], s2);
    }
}

// ---------------- fused GEMM (bf16 MFMA), 64-row tiles ----------------
// MODE 0: A = f32 src (h0)                         -> out = A @ W
// MODE 1: A = relu(bn3(relu(bn2(z))))  from bf16 z -> out = A @ W
// MODE 2: A = relu(bn1(y))             from bf16 y -> out = A @ W, banked stats(out)
template <int MODE>
__global__ __launch_bounds__(256) void gemm_mfma(
    const float* __restrict__ in_f,
    const ushort* __restrict__ in_h,
    const ushort* __restrict__ wt,
    const float* __restrict__ stP, const float* __restrict__ gP, const float* __restrict__ bP,
    const float* __restrict__ stQ, const float* __restrict__ gQ, const float* __restrict__ bQ,
    ushort* __restrict__ out,
    float* __restrict__ stats)
{
    __shared__ ushort WT[16384];
    __shared__ float scP[DD], shP[DD], scQ[DD], shQ[DD];

    const int t = threadIdx.x;
    const int lane = t & 63;
    const int wave = t >> 6;

    if (MODE >= 1 && t < DD) {
        float2 s12 = bank_sum(stP, t);
        float m = s12.x * (1.0f / NN);
        float var = s12.y * (1.0f / NN) - m * m;
        float s = gP[t] * rsqrtf(var + 1e-5f);
        scP[t] = s;
        shP[t] = fmaf(-m, s, bP[t]);
    }
    if (MODE == 1 && t < DD) {
        float2 s12 = bank_sum(stQ, t);
        float m = s12.x * (1.0f / NN);
        float var = s12.y * (1.0f / NN) - m * m;
        float s = gQ[t] * rsqrtf(var + 1e-5f);
        scQ[t] = s;
        shQ[t] = fmaf(-m, s, bQ[t]);
    }

    #pragma unroll
    for (int i = 0; i < 8; ++i) {
        int chunk = i * 4 + wave;
        gload_lds16(wt + (size_t)chunk * 512 + lane * 8, WT + chunk * 512);
    }
    __syncthreads();

    const int rgrp = wave >> 1;
    const int chalf = wave & 1;
    const int l15 = lane & 15, lg = lane >> 4;

    short8 Bf[4][4];
    #pragma unroll
    for (int jt = 0; jt < 4; ++jt) {
        int j = chalf * 64 + jt * 16 + l15;
        #pragma unroll
        for (int kk = 0; kk < 4; ++kk) {
            int slot = (kk * 4 + lg) ^ (j & 7);
            Bf[jt][kk] = *reinterpret_cast<const short8*>(WT + j * 128 + slot * 8);
        }
    }

    ushort (*Cst)[136] = reinterpret_cast<ushort(*)[136]>(WT);

    float psum[4] = {0.f, 0.f, 0.f, 0.f};
    float psq[4]  = {0.f, 0.f, 0.f, 0.f};

    #pragma unroll 1
    for (int s = 0; s < 2; ++s) {
        const int row0 = blockIdx.x * 64 + rgrp * 32 + s * 16;
        const bool active = row0 < NN;
        f32x4 acc[4] = {};

        if (active) {
            int row = row0 + l15;
            short8 Af[4];
            #pragma unroll
            for (int kk = 0; kk < 4; ++kk) {
                int kb = kk * 32 + lg * 8;
                float v[8];
                if (MODE == 0) {
                    const float* xr = in_f + (size_t)row * DD + kb;
                    float4 a0 = reinterpret_cast<const float4*>(xr)[0];
                    float4 a1 = reinterpret_cast<const float4*>(xr)[1];
                    v[0]=a0.x; v[1]=a0.y; v[2]=a0.z; v[3]=a0.w;
                    v[4]=a1.x; v[5]=a1.y; v[6]=a1.z; v[7]=a1.w;
                } else {
                    short8 raw = *reinterpret_cast<const short8*>(in_h + (size_t)row * DD + kb);
                    #pragma unroll
                    for (int q = 0; q < 8; ++q) v[q] = bf2f((ushort)raw[q]);
                    float4 p0 = *reinterpret_cast<const float4*>(&scP[kb]);
                    float4 p1 = *reinterpret_cast<const float4*>(&scP[kb + 4]);
                    float4 h0 = *reinterpret_cast<const float4*>(&shP[kb]);
                    float4 h1 = *reinterpret_cast<const float4*>(&shP[kb + 4]);
                    v[0]=fmaxf(fmaf(v[0],p0.x,h0.x),0.f);
                    v[1]=fmaxf(fmaf(v[1],p0.y,h0.y),0.f);
                    v[2]=fmaxf(fmaf(v[2],p0.z,h0.z),0.f);
                    v[3]=fmaxf(fmaf(v[3],p0.w,h0.w),0.f);
                    v[4]=fmaxf(fmaf(v[4],p1.x,h1.x),0.f);
                    v[5]=fmaxf(fmaf(v[5],p1.y,h1.y),0.f);
                    v[6]=fmaxf(fmaf(v[6],p1.z,h1.z),0.f);
                    v[7]=fmaxf(fmaf(v[7],p1.w,h1.w),0.f);
                    if (MODE == 1) {
                        float4 q0v = *reinterpret_cast<const float4*>(&scQ[kb]);
                        float4 q1v = *reinterpret_cast<const float4*>(&scQ[kb + 4]);
                        float4 r0v = *reinterpret_cast<const float4*>(&shQ[kb]);
                        float4 r1v = *reinterpret_cast<const float4*>(&shQ[kb + 4]);
                        v[0]=fmaxf(fmaf(v[0],q0v.x,r0v.x),0.f);
                        v[1]=fmaxf(fmaf(v[1],q0v.y,r0v.y),0.f);
                        v[2]=fmaxf(fmaf(v[2],q0v.z,r0v.z),0.f);
                        v[3]=fmaxf(fmaf(v[3],q0v.w,r0v.w),0.f);
                        v[4]=fmaxf(fmaf(v[4],q1v.x,r1v.x),0.f);
                        v[5]=fmaxf(fmaf(v[5],q1v.y,r1v.y),0.f);
                        v[6]=fmaxf(fmaf(v[6],q1v.z,r1v.z),0.f);
                        v[7]=fmaxf(fmaf(v[7],q1v.w,r1v.w),0.f);
                    }
                }
                short8 af;
                #pragma unroll
                for (int q = 0; q < 8; ++q) af[q] = (short)f2bf(v[q]);
                Af[kk] = af;
            }

            #pragma unroll
            for (int jt = 0; jt < 4; ++jt)
                #pragma unroll
                for (int kk = 0; kk < 4; ++kk)
                    acc[jt] = __builtin_amdgcn_mfma_f32_16x16x32_bf16(
                        Af[kk], Bf[jt][kk], acc[jt], 0, 0, 0);

            if (MODE == 2) {
                #pragma unroll
                for (int jt = 0; jt < 4; ++jt)
                    #pragma unroll
                    for (int i = 0; i < 4; ++i) {
                        float val = acc[jt][i];
                        psum[jt] += val;
                        psq[jt] += val * val;
                    }
            }
        }

        __syncthreads();
        if (active) {
            #pragma unroll
            for (int jt = 0; jt < 4; ++jt) {
                int col = chalf * 64 + jt * 16 + l15;
                #pragma unroll
                for (int i = 0; i < 4; ++i)
                    Cst[rgrp * 16 + lg * 4 + i][col] = f2bf(acc[jt][i]);
            }
        }
        __syncthreads();
        {
            int r = t >> 3, cg2 = t & 7;
            int lrow = (r < 16) ? (s * 16 + r) : (32 + s * 16 + (r - 16));
            int grow = blockIdx.x * 64 + lrow;
            if (grow < NN) {
                short8 v0 = *reinterpret_cast<const short8*>(&Cst[r][cg2 * 16]);
                short8 v1 = *reinterpret_cast<const short8*>(&Cst[r][cg2 * 16 + 8]);
                *reinterpret_cast<short8*>(out + (size_t)grow * DD + cg2 * 16) = v0;
                *reinterpret_cast<short8*>(out + (size_t)grow * DD + cg2 * 16 + 8) = v1;
            }
        }
    }

    if (MODE == 2) {
        float* stb = stats + (blockIdx.x & (NBANK - 1)) * 256;
        #pragma unroll
        for (int jt = 0; jt < 4; ++jt) {
            float s1 = psum[jt], s2 = psq[jt];
            s1 += __shfl_xor(s1, 16); s2 += __shfl_xor(s2, 16);
            s1 += __shfl_xor(s1, 32); s2 += __shfl_xor(s2, 32);
            if (lg == 0) {
                int f = chalf * 64 + jt * 16 + l15;
                atomicAdd(&stb[f], s1);
                atomicAdd(&stb[DD + f], s2);
            }
        }
    }
}

// ------- stats of relu(bn2(z)), bn2 params inline (banked in & out) -------
__global__ __launch_bounds__(256) void stats_relu(
    const ushort* __restrict__ z, const float* __restrict__ stin,
    const float* __restrict__ g, const float* __restrict__ b,
    float* __restrict__ stats)
{
    __shared__ float ssum[DD], ssq[DD], sc[DD], sh[DD];
    int t = threadIdx.x;
    if (t < DD) {
        ssum[t] = 0.f; ssq[t] = 0.f;
        float2 s12 = bank_sum(stin, t);
        float m = s12.x * (1.0f / NN);
        float var = s12.y * (1.0f / NN) - m * m;
        float s = g[t] * rsqrtf(var + 1e-5f);
        sc[t] = s;
        sh[t] = fmaf(-m, s, b[t]);
    }
    __syncthreads();

    int f = (t * 4) & 127;
    float4 scv = *reinterpret_cast<const float4*>(&sc[f]);
    float4 shv = *reinterpret_cast<const float4*>(&sh[f]);
    float p0=0,p1=0,p2=0,p3=0,q0=0,q1=0,q2=0,q3=0;
    size_t stride = (size_t)gridDim.x * 1024;
    for (size_t idx = (size_t)blockIdx.x * 1024 + t * 4; idx < (size_t)NN * DD; idx += stride) {
        uint2 zz = *reinterpret_cast<const uint2*>(z + idx);
        float u0 = fmaxf(fmaf(bflo(zz.x), scv.x, shv.x), 0.f);
        float u1 = fmaxf(fmaf(bfhi(zz.x), scv.y, shv.y), 0.f);
        float u2 = fmaxf(fmaf(bflo(zz.y), scv.z, shv.z), 0.f);
        float u3 = fmaxf(fmaf(bfhi(zz.y), scv.w, shv.w), 0.f);
        p0 += u0; q0 += u0 * u0;
        p1 += u1; q1 += u1 * u1;
        p2 += u2; q2 += u2 * u2;
        p3 += u3; q3 += u3 * u3;
    }
    atomicAdd(&ssum[f + 0], p0); atomicAdd(&ssq[f + 0], q0);
    atomicAdd(&ssum[f + 1], p1); atomicAdd(&ssq[f + 1], q1);
    atomicAdd(&ssum[f + 2], p2); atomicAdd(&ssq[f + 2], q2);
    atomicAdd(&ssum[f + 3], p3); atomicAdd(&ssq[f + 3], q3);
    __syncthreads();
    float* stb = stats + (blockIdx.x & (NBANK - 1)) * 256;
    if (t < DD) {
        atomicAdd(&stb[t], ssum[t]);
        atomicAdd(&stb[DD + t], ssq[t]);
    }
}

// ------- last layer: out = bn3(relu(bn2(z))) as f32 (banked stats in) -------
__global__ __launch_bounds__(256) void final_apply(
    const ushort* __restrict__ z,
    const float* __restrict__ st2in, const float* __restrict__ g2,
    const float* __restrict__ b2,
    const float* __restrict__ st3in, const float* __restrict__ g3,
    const float* __restrict__ b3,
    float* __restrict__ out)
{
    __shared__ float sc2[DD], sh2[DD], sc3[DD], sh3[DD];
    int t = threadIdx.x;
    if (t < DD) {
        float2 s12 = bank_sum(st2in, t);
        float m = s12.x * (1.0f / NN);
        float var = s12.y * (1.0f / NN) - m * m;
        float s = g2[t] * rsqrtf(var + 1e-5f);
        sc2[t] = s;
        sh2[t] = fmaf(-m, s, b2[t]);
        s12 = bank_sum(st3in, t);
        m = s12.x * (1.0f / NN);
        var = s12.y * (1.0f / NN) - m * m;
        s = g3[t] * rsqrtf(var + 1e-5f);
        sc3[t] = s;
        sh3[t] = fmaf(-m, s, b3[t]);
    }
    __syncthreads();

    int f = (t * 4) & 127;
    float4 s2 = *reinterpret_cast<const float4*>(&sc2[f]);
    float4 h2 = *reinterpret_cast<const float4*>(&sh2[f]);
    float4 s3 = *reinterpret_cast<const float4*>(&sc3[f]);
    float4 h3 = *reinterpret_cast<const float4*>(&sh3[f]);
    size_t stride = (size_t)gridDim.x * 1024;
    for (size_t idx = (size_t)blockIdx.x * 1024 + t * 4; idx < (size_t)NN * DD; idx += stride) {
        uint2 zz = *reinterpret_cast<const uint2*>(z + idx);
        float4 o;
        float u;
        u = fmaxf(fmaf(bflo(zz.x), s2.x, h2.x), 0.f); o.x = fmaf(u, s3.x, h3.x);
        u = fmaxf(fmaf(bfhi(zz.x), s2.y, h2.y), 0.f); o.y = fmaf(u, s3.y, h3.y);
        u = fmaxf(fmaf(bflo(zz.y), s2.z, h2.z), 0.f); o.z = fmaf(u, s3.z, h3.z);
        u = fmaxf(fmaf(bfhi(zz.y), s2.w, h2.w), 0.f); o.w = fmaf(u, s3.w, h3.w);
        *reinterpret_cast<float4*>(out + idx) = o;
    }
}

extern "C" void kernel_launch(void* const* d_in, const int* in_sizes, int n_in,
                              void* d_out, int out_size, void* d_ws, size_t ws_size,
                              hipStream_t stream)
{
    const float* h0   = (const float*)d_in[0];
    const int*  edges = (const int*)d_in[1];
    const float* w    = (const float*)d_in[2];
    const float* W0s  = (const float*)d_in[3];
    const float* W1s  = (const float*)d_in[4];
    const float* bn1g = (const float*)d_in[5];
    const float* bn1b = (const float*)d_in[6];
    const float* bn2g = (const float*)d_in[7];
    const float* bn2b = (const float*)d_in[8];
    const float* bn3g = (const float*)d_in[9];
    const float* bn3b = (const float*)d_in[10];
    float* out = (float*)d_out;

    const size_t ND = (size_t)NN * DD;
    ushort* y0buf = (ushort*)d_ws;
    ushort* ybuf  = y0buf + ND;
    ushort* zbuf  = ybuf + ND;
    ushort* wtbuf = zbuf + ND;                    // 6 x 16384 ushorts
    float*  stats = (float*)(wtbuf + 6 * 16384);  // 9 stages x SB
    int*    deg      = (int*)(stats + 9 * SB);
    int*    off      = deg + NN;                  // NN+1
    int*    bcur     = off + NN + 1;              // NBKT
    int*    partials = bcur + NBKT;               // NB
    int2*   em       = (int2*)(partials + NB + 2);  // EE (8B-aligned)
    int2*   stg      = em + EE;                     // EE staging

    const int* src = edges;
    const int* dst = edges + EE;

    prep_w<<<NB, 256, 0, stream>>>(W0s, W1s, wtbuf, deg, stats);
    hist_kernel<<<(EE + 255) / 256, 256, 0, stream>>>(dst, deg);
    scan_a<<<NB, 256, 0, stream>>>(deg, partials);
    scan_c<<<NB, 256, 0, stream>>>(deg, partials, off, bcur);
    bin_stage1<<<B1G, 256, 0, stream>>>(src, dst, w, bcur, stg);
    bin_stage2<<<NBKT, 256, 0, stream>>>(off, stg, em);

    const int GG = (NN + 63) / 64;   // gemm blocks (64-row tiles)

    for (int i = 0; i < LL; ++i) {
        float* st0 = stats + (i * 3 + 0) * SB;
        float* st1 = stats + (i * 3 + 1) * SB;
        float* st2 = stats + (i * 3 + 2) * SB;
        const ushort* wt0 = wtbuf + (size_t)i * 16384;
        const ushort* wt1 = wtbuf + (size_t)(i + 3) * 16384;

        if (i == 0) {
            gemm_mfma<0><<<GG, 256, 0, stream>>>(
                h0, nullptr, wt0,
                nullptr, nullptr, nullptr, nullptr, nullptr, nullptr,
                y0buf, nullptr);
        } else {
            float* st1p = stats + ((i - 1) * 3 + 1) * SB;
            float* st2p = stats + ((i - 1) * 3 + 2) * SB;
            gemm_mfma<1><<<GG, 256, 0, stream>>>(
                nullptr, zbuf, wt0,
                st1p, bn2g + (i - 1) * DD, bn2b + (i - 1) * DD,
                st2p, bn3g + (i - 1) * DD, bn3b + (i - 1) * DD,
                y0buf, nullptr);
        }

        gather_kernel<<<GA, 256, 0, stream>>>(y0buf, off, (const long long*)em, ybuf, st0);

        gemm_mfma<2><<<GG, 256, 0, stream>>>(
            nullptr, ybuf, wt1,
            st0, bn1g + i * DD, bn1b + i * DD,
            nullptr, nullptr, nullptr,
            zbuf, st1);

        stats_relu<<<1024, 256, 0, stream>>>(zbuf, st1, bn2g + i * DD, bn2b + i * DD, st2);
    }

    final_apply<<<2048, 256, 0, stream>>>(
        zbuf,
        stats + (2 * 3 + 1) * SB, bn2g + 2 * DD, bn2b + 2 * DD,
        stats + (2 * 3 + 2) * SB, bn3g + 2 * DD, bn3b + 2 * DD,
        out);
}

// Round 19
// 284.243 us; speedup vs baseline: 1.0305x; 1.0305x over previous
//
#include <hip/hip_runtime.h>
#include <stdint.h>

#define NN 50000
#define EE 600000
#define DD 128
#define LL 3
#define NB 196    // ceil(NN/256)
#define NBKT 196  // buckets of 256 nodes
#define NBANK 16
#define SB (NBANK * 256)  // floats per banked stats stage
#define GA 3125           // gather blocks: 16 nodes/block, GA*16 == NN exactly
#define B1CH 2048         // stage-1 chunk (edges per block)
#define B1G ((EE + B1CH - 1) / B1CH)

typedef __attribute__((ext_vector_type(8))) short short8;
typedef __attribute__((ext_vector_type(4))) float f32x4;
typedef __attribute__((ext_vector_type(4))) unsigned int u32x4;

static __device__ __forceinline__ ushort f2bf(float f) {
    uint32_t u = __builtin_bit_cast(uint32_t, f);
    u += 0x7FFFu + ((u >> 16) & 1u);
    return (ushort)(u >> 16);
}
static __device__ __forceinline__ float bf2f(ushort u) {
    uint32_t x = ((uint32_t)u) << 16;
    return __builtin_bit_cast(float, x);
}
static __device__ __forceinline__ float bflo(uint32_t p) { return bf2f((ushort)(p & 0xffffu)); }
static __device__ __forceinline__ float bfhi(uint32_t p) { return bf2f((ushort)(p >> 16)); }

static __device__ __forceinline__ void gload_lds16(const void* g, void* l) {
    __builtin_amdgcn_global_load_lds(
        (const __attribute__((address_space(1))) uint32_t*)g,
        (__attribute__((address_space(3))) uint32_t*)l, 16, 0, 0);
}

static __device__ __forceinline__ float2 bank_sum(const float* st, int t) {
    float s1 = 0.f, s2 = 0.f;
    #pragma unroll
    for (int bb = 0; bb < NBANK; ++bb) {
        s1 += st[bb * 256 + t];
        s2 += st[bb * 256 + DD + t];
    }
    return make_float2(s1, s2);
}

// ------- prep: W -> W^T bf16 slot-swizzled (blocks 0..11) + zero deg/stats -------
__global__ __launch_bounds__(256) void prep_w(
    const float* __restrict__ W0s, const float* __restrict__ W1s,
    ushort* __restrict__ wt, int* __restrict__ deg, float* __restrict__ stats)
{
    __shared__ float ws[8192];
    const int b = blockIdx.x;
    const int t = threadIdx.x;

    {
        int i = b * 256 + t;
        if (i < NN) deg[i] = 0;
        if (b >= 12 && b < 12 + 9 * NBANK) stats[(b - 12) * 256 + t] = 0.f;
    }

    if (b < 12) {
        const int m = b >> 1, kh = b & 1;
        const float* W = (m < 3 ? W0s + (size_t)m * 16384
                                : W1s + (size_t)(m - 3) * 16384) + (size_t)kh * 64 * 128;
        #pragma unroll
        for (int i = 0; i < 8; ++i) {
            int i4 = t + i * 256;
            reinterpret_cast<float4*>(ws)[i4] = reinterpret_cast<const float4*>(W)[i4];
        }
        __syncthreads();
        ushort* out = wt + (size_t)m * 16384;
        const int j = t & 127;
        const int rep = t >> 7;
        #pragma unroll
        for (int si = 0; si < 4; ++si) {
            int s = kh * 8 + rep * 4 + si;
            int kloc = (rep * 4 + si) * 8;
            short8 pk;
            #pragma unroll
            for (int q = 0; q < 8; ++q) pk[q] = (short)f2bf(ws[(kloc + q) * 128 + j]);
            int slot = s ^ (j & 7);
            *reinterpret_cast<short8*>(out + j * 128 + slot * 8) = pk;
        }
    }
}

// ---------------- CSR build ----------------
__global__ __launch_bounds__(256) void hist_kernel(
    const int* __restrict__ dst, int* __restrict__ deg)
{
    int e = blockIdx.x * 256 + threadIdx.x;
    if (e < EE) atomicAdd(&deg[dst[e]], 1);
}

__global__ __launch_bounds__(256) void scan_a(
    const int* __restrict__ deg, int* __restrict__ partials)
{
    int i = blockIdx.x * 256 + threadIdx.x;
    int v = (i < NN) ? deg[i] : 0;
    #pragma unroll
    for (int d = 1; d < 64; d <<= 1) v += __shfl_xor(v, d);
    __shared__ int wsum[4];
    if ((threadIdx.x & 63) == 0) wsum[threadIdx.x >> 6] = v;
    __syncthreads();
    if (threadIdx.x == 0)
        partials[blockIdx.x] = wsum[0] + wsum[1] + wsum[2] + wsum[3];
}

__global__ __launch_bounds__(256) void scan_c(
    const int* __restrict__ deg, const int* __restrict__ partials,
    int* __restrict__ off, int* __restrict__ bcur)
{
    __shared__ int ps[256], s[256];
    const int t = threadIdx.x;
    int pv = (t < NB) ? partials[t] : 0;
    ps[t] = pv;
    __syncthreads();
    for (int d = 1; d < 256; d <<= 1) {
        int u = (t >= d) ? ps[t - d] : 0;
        __syncthreads();
        ps[t] += u;
        __syncthreads();
    }
    int base = (blockIdx.x > 0) ? ps[blockIdx.x - 1] : 0;

    int i = blockIdx.x * 256 + t;
    int v = (i < NN) ? deg[i] : 0;
    s[t] = v;
    __syncthreads();
    for (int d = 1; d < 256; d <<= 1) {
        int u = (t >= d) ? s[t - d] : 0;
        __syncthreads();
        s[t] += u;
        __syncthreads();
    }
    int excl = base + s[t] - v;
    if (i < NN) {
        off[i] = excl;
        if ((i & 255) == 0) bcur[i >> 8] = excl;
    }
    if (i == 0) off[NN] = EE;
}

// ------- binsort stage 1: chunk-local count -> reserve -> place into staging -------
__global__ __launch_bounds__(256) void bin_stage1(
    const int* __restrict__ src, const int* __restrict__ dst,
    const float* __restrict__ w, int* __restrict__ bcur,
    int2* __restrict__ stg)
{
    __shared__ int cnt[NBKT], gb[NBKT];
    const int t = threadIdx.x;
    const int e0 = blockIdx.x * B1CH;
    for (int b = t; b < NBKT; b += 256) cnt[b] = 0;
    __syncthreads();
    #pragma unroll
    for (int k = 0; k < B1CH / 256; ++k) {
        int e = e0 + k * 256 + t;
        if (e < EE) atomicAdd(&cnt[dst[e] >> 8], 1);
    }
    __syncthreads();
    for (int b = t; b < NBKT; b += 256) {
        int c = cnt[b];
        if (c > 0) gb[b] = atomicAdd(&bcur[b], c);
        cnt[b] = 0;
    }
    __syncthreads();
    #pragma unroll
    for (int k = 0; k < B1CH / 256; ++k) {
        int e = e0 + k * 256 + t;
        if (e < EE) {
            int d = dst[e];
            int b = d >> 8;
            int p = gb[b] + atomicAdd(&cnt[b], 1);
            stg[p] = make_int2((d << 16) | src[e], __float_as_int(w[e]));
        }
    }
}

// ------- binsort stage 2: per-bucket scatter into final em (XCD-local) -------
__global__ __launch_bounds__(256) void bin_stage2(
    const int* __restrict__ off, const int2* __restrict__ stg,
    int2* __restrict__ em)
{
    __shared__ int lcur[256];
    const int t = threadIdx.x;
    const int b = blockIdx.x;
    const int n0 = b * 256;
    int nidx = n0 + t;
    lcur[t] = (nidx < NN) ? off[nidx] : EE;
    int hi = n0 + 256; if (hi > NN) hi = NN;
    const int rbeg = off[n0];
    const int rend = off[hi];
    __syncthreads();
    for (int p = rbeg + t; p < rend; p += 256) {
        int2 en = stg[p];
        uint32_t key = (uint32_t)en.x;
        int d_local = (int)(key >> 16) & 255;
        int srcv = (int)(key & 0xffffu);
        int pos = atomicAdd(&lcur[d_local], 1);
        em[pos] = make_int2(srcv, en.y);
    }
}

// ------- gather + fused BN1 stats (shuffle-reduced): y[v]=y0[v]+sum w*y0[src] -------
__global__ __launch_bounds__(256) void gather_kernel(
    const ushort* __restrict__ y0, const int* __restrict__ off,
    const long long* __restrict__ em, ushort* __restrict__ y,
    float* __restrict__ st0)
{
    __shared__ float red[4][256];
    const int t = threadIdx.x;
    const int wave = t >> 6, lane = t & 63;
    const int qw = lane >> 4, ql = lane & 15;
    const int v = blockIdx.x * 16 + wave * 4 + qw;

    const int beg = off[v], end = off[v + 1];
    const ushort* rowbase = y0 + ql * 8;

    uint4 sw = *reinterpret_cast<const uint4*>(y0 + (size_t)v * DD + ql * 8);
    float a0 = bflo(sw.x), a1 = bfhi(sw.x), a2 = bflo(sw.y), a3 = bfhi(sw.y);
    float a4 = bflo(sw.z), a5 = bfhi(sw.z), a6 = bflo(sw.w), a7 = bfhi(sw.w);

    int j = beg;
    for (; j + 3 < end; j += 4) {
        long long q0 = __builtin_nontemporal_load(&em[j]);
        long long q1 = __builtin_nontemporal_load(&em[j + 1]);
        long long q2 = __builtin_nontemporal_load(&em[j + 2]);
        long long q3 = __builtin_nontemporal_load(&em[j + 3]);
        int s0 = (int)(q0 & 0xffffffffLL), s1 = (int)(q1 & 0xffffffffLL);
        int s2 = (int)(q2 & 0xffffffffLL), s3 = (int)(q3 & 0xffffffffLL);
        float w0 = __int_as_float((int)(q0 >> 32)), w1 = __int_as_float((int)(q1 >> 32));
        float w2 = __int_as_float((int)(q2 >> 32)), w3 = __int_as_float((int)(q3 >> 32));
        uint4 p0 = *reinterpret_cast<const uint4*>(rowbase + (size_t)s0 * DD);
        uint4 p1 = *reinterpret_cast<const uint4*>(rowbase + (size_t)s1 * DD);
        uint4 p2 = *reinterpret_cast<const uint4*>(rowbase + (size_t)s2 * DD);
        uint4 p3 = *reinterpret_cast<const uint4*>(rowbase + (size_t)s3 * DD);
        a0 = fmaf(w0, bflo(p0.x), a0); a1 = fmaf(w0, bfhi(p0.x), a1);
        a2 = fmaf(w0, bflo(p0.y), a2); a3 = fmaf(w0, bfhi(p0.y), a3);
        a4 = fmaf(w0, bflo(p0.z), a4); a5 = fmaf(w0, bfhi(p0.z), a5);
        a6 = fmaf(w0, bflo(p0.w), a6); a7 = fmaf(w0, bfhi(p0.w), a7);
        a0 = fmaf(w1, bflo(p1.x), a0); a1 = fmaf(w1, bfhi(p1.x), a1);
        a2 = fmaf(w1, bflo(p1.y), a2); a3 = fmaf(w1, bfhi(p1.y), a3);
        a4 = fmaf(w1, bflo(p1.z), a4); a5 = fmaf(w1, bfhi(p1.z), a5);
        a6 = fmaf(w1, bflo(p1.w), a6); a7 = fmaf(w1, bfhi(p1.w), a7);
        a0 = fmaf(w2, bflo(p2.x), a0); a1 = fmaf(w2, bfhi(p2.x), a1);
        a2 = fmaf(w2, bflo(p2.y), a2); a3 = fmaf(w2, bfhi(p2.y), a3);
        a4 = fmaf(w2, bflo(p2.z), a4); a5 = fmaf(w2, bfhi(p2.z), a5);
        a6 = fmaf(w2, bflo(p2.w), a6); a7 = fmaf(w2, bfhi(p2.w), a7);
        a0 = fmaf(w3, bflo(p3.x), a0); a1 = fmaf(w3, bfhi(p3.x), a1);
        a2 = fmaf(w3, bflo(p3.y), a2); a3 = fmaf(w3, bfhi(p3.y), a3);
        a4 = fmaf(w3, bflo(p3.z), a4); a5 = fmaf(w3, bfhi(p3.z), a5);
        a6 = fmaf(w3, bflo(p3.w), a6); a7 = fmaf(w3, bfhi(p3.w), a7);
    }
    for (; j < end; ++j) {
        long long q0 = __builtin_nontemporal_load(&em[j]);
        int s0 = (int)(q0 & 0xffffffffLL);
        float w0 = __int_as_float((int)(q0 >> 32));
        uint4 p0 = *reinterpret_cast<const uint4*>(rowbase + (size_t)s0 * DD);
        a0 = fmaf(w0, bflo(p0.x), a0); a1 = fmaf(w0, bfhi(p0.x), a1);
        a2 = fmaf(w0, bflo(p0.y), a2); a3 = fmaf(w0, bfhi(p0.y), a3);
        a4 = fmaf(w0, bflo(p0.z), a4); a5 = fmaf(w0, bfhi(p0.z), a5);
        a6 = fmaf(w0, bflo(p0.w), a6); a7 = fmaf(w0, bfhi(p0.w), a7);
    }
    ushort r0 = f2bf(a0), r1 = f2bf(a1), r2 = f2bf(a2), r3 = f2bf(a3);
    ushort r4 = f2bf(a4), r5 = f2bf(a5), r6 = f2bf(a6), r7 = f2bf(a7);
    u32x4 ow;
    ow.x = (uint32_t)r0 | ((uint32_t)r1 << 16);
    ow.y = (uint32_t)r2 | ((uint32_t)r3 << 16);
    ow.z = (uint32_t)r4 | ((uint32_t)r5 << 16);
    ow.w = (uint32_t)r6 | ((uint32_t)r7 << 16);
    __builtin_nontemporal_store(ow, reinterpret_cast<u32x4*>(y + (size_t)v * DD + ql * 8));

    float b[8], q[8];
    b[0] = bf2f(r0); b[1] = bf2f(r1); b[2] = bf2f(r2); b[3] = bf2f(r3);
    b[4] = bf2f(r4); b[5] = bf2f(r5); b[6] = bf2f(r6); b[7] = bf2f(r7);
    #pragma unroll
    for (int k = 0; k < 8; ++k) {
        q[k] = b[k] * b[k];
        b[k] += __shfl_xor(b[k], 16); q[k] += __shfl_xor(q[k], 16);
        b[k] += __shfl_xor(b[k], 32); q[k] += __shfl_xor(q[k], 32);
    }
    if (qw == 0) {
        #pragma unroll
        for (int k = 0; k < 8; ++k) {
            red[wave][ql * 8 + k] = b[k];
            red[wave][128 + ql * 8 + k] = q[k];
        }
    }
    __syncthreads();
    if (t < 128) {
        float s1 = red[0][t] + red[1][t] + red[2][t] + red[3][t];
        float s2 = red[0][128 + t] + red[1][128 + t] + red[2][128 + t] + red[3][128 + t];
        float* stb = st0 + (blockIdx.x & (NBANK - 1)) * 256;
        atomicAdd(&stb[t], s1);
        atomicAdd(&stb[DD + t], s2);
    }
}

// ---------------- fused GEMM (bf16 MFMA), 128-row tiles ----------------
template <int MODE>
__global__ __launch_bounds__(256) void gemm_mfma(
    const float* __restrict__ in_f,
    const ushort* __restrict__ in_h,
    const ushort* __restrict__ wt,
    const float* __restrict__ stP, const float* __restrict__ gP, const float* __restrict__ bP,
    const float* __restrict__ stQ, const float* __restrict__ gQ, const float* __restrict__ bQ,
    ushort* __restrict__ out,
    float* __restrict__ stats)
{
    __shared__ ushort WT[16384];
    __shared__ float scP[DD], shP[DD], scQ[DD], shQ[DD];

    const int t = threadIdx.x;
    const int lane = t & 63;
    const int wave = t >> 6;

    if (MODE >= 1 && t < DD) {
        float2 s12 = bank_sum(stP, t);
        float m = s12.x * (1.0f / NN);
        float var = s12.y * (1.0f / NN) - m * m;
        float s = gP[t] * rsqrtf(var + 1e-5f);
        scP[t] = s;
        shP[t] = fmaf(-m, s, bP[t]);
    }
    if (MODE == 1 && t < DD) {
        float2 s12 = bank_sum(stQ, t);
        float m = s12.x * (1.0f / NN);
        float var = s12.y * (1.0f / NN) - m * m;
        float s = gQ[t] * rsqrtf(var + 1e-5f);
        scQ[t] = s;
        shQ[t] = fmaf(-m, s, bQ[t]);
    }

    #pragma unroll
    for (int i = 0; i < 8; ++i) {
        int chunk = i * 4 + wave;
        gload_lds16(wt + (size_t)chunk * 512 + lane * 8, WT + chunk * 512);
    }
    __syncthreads();

    const int rgrp = wave >> 1;
    const int chalf = wave & 1;
    const int l15 = lane & 15, lg = lane >> 4;

    short8 Bf[4][4];
    #pragma unroll
    for (int jt = 0; jt < 4; ++jt) {
        int j = chalf * 64 + jt * 16 + l15;
        #pragma unroll
        for (int kk = 0; kk < 4; ++kk) {
            int slot = (kk * 4 + lg) ^ (j & 7);
            Bf[jt][kk] = *reinterpret_cast<const short8*>(WT + j * 128 + slot * 8);
        }
    }

    ushort (*Cst)[136] = reinterpret_cast<ushort(*)[136]>(WT);

    float psum[4] = {0.f, 0.f, 0.f, 0.f};
    float psq[4]  = {0.f, 0.f, 0.f, 0.f};

    #pragma unroll 1
    for (int s = 0; s < 4; ++s) {
        const int row0 = blockIdx.x * 128 + rgrp * 64 + s * 16;
        const bool active = row0 < NN;
        f32x4 acc[4] = {};

        if (active) {
            int row = row0 + l15;
            short8 Af[4];
            #pragma unroll
            for (int kk = 0; kk < 4; ++kk) {
                int kb = kk * 32 + lg * 8;
                float v[8];
                if (MODE == 0) {
                    const float* xr = in_f + (size_t)row * DD + kb;
                    float4 a0 = reinterpret_cast<const float4*>(xr)[0];
                    float4 a1 = reinterpret_cast<const float4*>(xr)[1];
                    v[0]=a0.x; v[1]=a0.y; v[2]=a0.z; v[3]=a0.w;
                    v[4]=a1.x; v[5]=a1.y; v[6]=a1.z; v[7]=a1.w;
                } else {
                    short8 raw = *reinterpret_cast<const short8*>(in_h + (size_t)row * DD + kb);
                    #pragma unroll
                    for (int q = 0; q < 8; ++q) v[q] = bf2f((ushort)raw[q]);
                    float4 p0 = *reinterpret_cast<const float4*>(&scP[kb]);
                    float4 p1 = *reinterpret_cast<const float4*>(&scP[kb + 4]);
                    float4 h0 = *reinterpret_cast<const float4*>(&shP[kb]);
                    float4 h1 = *reinterpret_cast<const float4*>(&shP[kb + 4]);
                    v[0]=fmaxf(fmaf(v[0],p0.x,h0.x),0.f);
                    v[1]=fmaxf(fmaf(v[1],p0.y,h0.y),0.f);
                    v[2]=fmaxf(fmaf(v[2],p0.z,h0.z),0.f);
                    v[3]=fmaxf(fmaf(v[3],p0.w,h0.w),0.f);
                    v[4]=fmaxf(fmaf(v[4],p1.x,h1.x),0.f);
                    v[5]=fmaxf(fmaf(v[5],p1.y,h1.y),0.f);
                    v[6]=fmaxf(fmaf(v[6],p1.z,h1.z),0.f);
                    v[7]=fmaxf(fmaf(v[7],p1.w,h1.w),0.f);
                    if (MODE == 1) {
                        float4 q0v = *reinterpret_cast<const float4*>(&scQ[kb]);
                        float4 q1v = *reinterpret_cast<const float4*>(&scQ[kb + 4]);
                        float4 r0v = *reinterpret_cast<const float4*>(&shQ[kb]);
                        float4 r1v = *reinterpret_cast<const float4*>(&shQ[kb + 4]);
                        v[0]=fmaxf(fmaf(v[0],q0v.x,r0v.x),0.f);
                        v[1]=fmaxf(fmaf(v[1],q0v.y,r0v.y),0.f);
                        v[2]=fmaxf(fmaf(v[2],q0v.z,r0v.z),0.f);
                        v[3]=fmaxf(fmaf(v[3],q0v.w,r0v.w),0.f);
                        v[4]=fmaxf(fmaf(v[4],q1v.x,r1v.x),0.f);
                        v[5]=fmaxf(fmaf(v[5],q1v.y,r1v.y),0.f);
                        v[6]=fmaxf(fmaf(v[6],q1v.z,r1v.z),0.f);
                        v[7]=fmaxf(fmaf(v[7],q1v.w,r1v.w),0.f);
                    }
                }
                short8 af;
                #pragma unroll
                for (int q = 0; q < 8; ++q) af[q] = (short)f2bf(v[q]);
                Af[kk] = af;
            }

            #pragma unroll
            for (int jt = 0; jt < 4; ++jt)
                #pragma unroll
                for (int kk = 0; kk < 4; ++kk)
                    acc[jt] = __builtin_amdgcn_mfma_f32_16x16x32_bf16(
                        Af[kk], Bf[jt][kk], acc[jt], 0, 0, 0);

            if (MODE == 2) {
                #pragma unroll
                for (int jt = 0; jt < 4; ++jt)
                    #pragma unroll
                    for (int i = 0; i < 4; ++i) {
                        float val = acc[jt][i];
                        psum[jt] += val;
                        psq[jt] += val * val;
                    }
            }
        }

        __syncthreads();
        if (active) {
            #pragma unroll
            for (int jt = 0; jt < 4; ++jt) {
                int col = chalf * 64 + jt * 16 + l15;
                #pragma unroll
                for (int i = 0; i < 4; ++i)
                    Cst[rgrp * 16 + lg * 4 + i][col] = f2bf(acc[jt][i]);
            }
        }
        __syncthreads();
        {
            int r = t >> 3, cg2 = t & 7;
            int lrow = (r < 16) ? (s * 16 + r) : (64 + s * 16 + (r - 16));
            int grow = blockIdx.x * 128 + lrow;
            if (grow < NN) {
                short8 v0 = *reinterpret_cast<const short8*>(&Cst[r][cg2 * 16]);
                short8 v1 = *reinterpret_cast<const short8*>(&Cst[r][cg2 * 16 + 8]);
                *reinterpret_cast<short8*>(out + (size_t)grow * DD + cg2 * 16) = v0;
                *reinterpret_cast<short8*>(out + (size_t)grow * DD + cg2 * 16 + 8) = v1;
            }
        }
    }

    if (MODE == 2) {
        float* stb = stats + (blockIdx.x & (NBANK - 1)) * 256;
        #pragma unroll
        for (int jt = 0; jt < 4; ++jt) {
            float s1 = psum[jt], s2 = psq[jt];
            s1 += __shfl_xor(s1, 16); s2 += __shfl_xor(s2, 16);
            s1 += __shfl_xor(s1, 32); s2 += __shfl_xor(s2, 32);
            if (lg == 0) {
                int f = chalf * 64 + jt * 16 + l15;
                atomicAdd(&stb[f], s1);
                atomicAdd(&stb[DD + f], s2);
            }
        }
    }
}

// ------- stats of relu(bn2(z)), bn2 params inline (banked in & out) -------
__global__ __launch_bounds__(256) void stats_relu(
    const ushort* __restrict__ z, const float* __restrict__ stin,
    const float* __restrict__ g, const float* __restrict__ b,
    float* __restrict__ stats)
{
    __shared__ float ssum[DD], ssq[DD], sc[DD], sh[DD];
    int t = threadIdx.x;
    if (t < DD) {
        ssum[t] = 0.f; ssq[t] = 0.f;
        float2 s12 = bank_sum(stin, t);
        float m = s12.x * (1.0f / NN);
        float var = s12.y * (1.0f / NN) - m * m;
        float s = g[t] * rsqrtf(var + 1e-5f);
        sc[t] = s;
        sh[t] = fmaf(-m, s, b[t]);
    }
    __syncthreads();

    int f = (t * 4) & 127;
    float4 scv = *reinterpret_cast<const float4*>(&sc[f]);
    float4 shv = *reinterpret_cast<const float4*>(&sh[f]);
    float p0=0,p1=0,p2=0,p3=0,q0=0,q1=0,q2=0,q3=0;
    size_t stride = (size_t)gridDim.x * 1024;
    for (size_t idx = (size_t)blockIdx.x * 1024 + t * 4; idx < (size_t)NN * DD; idx += stride) {
        uint2 zz = *reinterpret_cast<const uint2*>(z + idx);
        float u0 = fmaxf(fmaf(bflo(zz.x), scv.x, shv.x), 0.f);
        float u1 = fmaxf(fmaf(bfhi(zz.x), scv.y, shv.y), 0.f);
        float u2 = fmaxf(fmaf(bflo(zz.y), scv.z, shv.z), 0.f);
        float u3 = fmaxf(fmaf(bfhi(zz.y), scv.w, shv.w), 0.f);
        p0 += u0; q0 += u0 * u0;
        p1 += u1; q1 += u1 * u1;
        p2 += u2; q2 += u2 * u2;
        p3 += u3; q3 += u3 * u3;
    }
    atomicAdd(&ssum[f + 0], p0); atomicAdd(&ssq[f + 0], q0);
    atomicAdd(&ssum[f + 1], p1); atomicAdd(&ssq[f + 1], q1);
    atomicAdd(&ssum[f + 2], p2); atomicAdd(&ssq[f + 2], q2);
    atomicAdd(&ssum[f + 3], p3); atomicAdd(&ssq[f + 3], q3);
    __syncthreads();
    float* stb = stats + (blockIdx.x & (NBANK - 1)) * 256;
    if (t < DD) {
        atomicAdd(&stb[t], ssum[t]);
        atomicAdd(&stb[DD + t], ssq[t]);
    }
}

// ------- last layer: out = bn3(relu(bn2(z))) as f32 (banked stats in) -------
__global__ __launch_bounds__(256) void final_apply(
    const ushort* __restrict__ z,
    const float* __restrict__ st2in, const float* __restrict__ g2,
    const float* __restrict__ b2,
    const float* __restrict__ st3in, const float* __restrict__ g3,
    const float* __restrict__ b3,
    float* __restrict__ out)
{
    __shared__ float sc2[DD], sh2[DD], sc3[DD], sh3[DD];
    int t = threadIdx.x;
    if (t < DD) {
        float2 s12 = bank_sum(st2in, t);
        float m = s12.x * (1.0f / NN);
        float var = s12.y * (1.0f / NN) - m * m;
        float s = g2[t] * rsqrtf(var + 1e-5f);
        sc2[t] = s;
        sh2[t] = fmaf(-m, s, b2[t]);
        s12 = bank_sum(st3in, t);
        m = s12.x * (1.0f / NN);
        var = s12.y * (1.0f / NN) - m * m;
        s = g3[t] * rsqrtf(var + 1e-5f);
        sc3[t] = s;
        sh3[t] = fmaf(-m, s, b3[t]);
    }
    __syncthreads();

    int f = (t * 4) & 127;
    float4 s2 = *reinterpret_cast<const float4*>(&sc2[f]);
    float4 h2 = *reinterpret_cast<const float4*>(&sh2[f]);
    float4 s3 = *reinterpret_cast<const float4*>(&sc3[f]);
    float4 h3 = *reinterpret_cast<const float4*>(&sh3[f]);
    size_t stride = (size_t)gridDim.x * 1024;
    for (size_t idx = (size_t)blockIdx.x * 1024 + t * 4; idx < (size_t)NN * DD; idx += stride) {
        uint2 zz = *reinterpret_cast<const uint2*>(z + idx);
        float4 o;
        float u;
        u = fmaxf(fmaf(bflo(zz.x), s2.x, h2.x), 0.f); o.x = fmaf(u, s3.x, h3.x);
        u = fmaxf(fmaf(bfhi(zz.x), s2.y, h2.y), 0.f); o.y = fmaf(u, s3.y, h3.y);
        u = fmaxf(fmaf(bflo(zz.y), s2.z, h2.z), 0.f); o.z = fmaf(u, s3.z, h3.z);
        u = fmaxf(fmaf(bfhi(zz.y), s2.w, h2.w), 0.f); o.w = fmaf(u, s3.w, h3.w);
        *reinterpret_cast<float4*>(out + idx) = o;
    }
}

extern "C" void kernel_launch(void* const* d_in, const int* in_sizes, int n_in,
                              void* d_out, int out_size, void* d_ws, size_t ws_size,
                              hipStream_t stream)
{
    const float* h0   = (const float*)d_in[0];
    const int*  edges = (const int*)d_in[1];
    const float* w    = (const float*)d_in[2];
    const float* W0s  = (const float*)d_in[3];
    const float* W1s  = (const float*)d_in[4];
    const float* bn1g = (const float*)d_in[5];
    const float* bn1b = (const float*)d_in[6];
    const float* bn2g = (const float*)d_in[7];
    const float* bn2b = (const float*)d_in[8];
    const float* bn3g = (const float*)d_in[9];
    const float* bn3b = (const float*)d_in[10];
    float* out = (float*)d_out;

    const size_t ND = (size_t)NN * DD;
    ushort* y0buf = (ushort*)d_ws;
    ushort* ybuf  = y0buf + ND;
    ushort* zbuf  = ybuf + ND;
    ushort* wtbuf = zbuf + ND;                    // 6 x 16384 ushorts
    float*  stats = (float*)(wtbuf + 6 * 16384);  // 9 stages x SB
    int*    deg      = (int*)(stats + 9 * SB);
    int*    off      = deg + NN;                  // NN+1
    int*    bcur     = off + NN + 1;              // NBKT
    int*    partials = bcur + NBKT;               // NB
    int2*   em       = (int2*)(partials + NB + 2);  // EE (8B-aligned)
    int2*   stg      = em + EE;                     // EE staging

    const int* src = edges;
    const int* dst = edges + EE;

    prep_w<<<NB, 256, 0, stream>>>(W0s, W1s, wtbuf, deg, stats);
    hist_kernel<<<(EE + 255) / 256, 256, 0, stream>>>(dst, deg);
    scan_a<<<NB, 256, 0, stream>>>(deg, partials);
    scan_c<<<NB, 256, 0, stream>>>(deg, partials, off, bcur);
    bin_stage1<<<B1G, 256, 0, stream>>>(src, dst, w, bcur, stg);
    bin_stage2<<<NBKT, 256, 0, stream>>>(off, stg, em);

    const int GG = (NN + 127) / 128;   // gemm blocks (128-row tiles)

    for (int i = 0; i < LL; ++i) {
        float* st0 = stats + (i * 3 + 0) * SB;
        float* st1 = stats + (i * 3 + 1) * SB;
        float* st2 = stats + (i * 3 + 2) * SB;
        const ushort* wt0 = wtbuf + (size_t)i * 16384;
        const ushort* wt1 = wtbuf + (size_t)(i + 3) * 16384;

        if (i == 0) {
            gemm_mfma<0><<<GG, 256, 0, stream>>>(
                h0, nullptr, wt0,
                nullptr, nullptr, nullptr, nullptr, nullptr, nullptr,
                y0buf, nullptr);
        } else {
            float* st1p = stats + ((i - 1) * 3 + 1) * SB;
            float* st2p = stats + ((i - 1) * 3 + 2) * SB;
            gemm_mfma<1><<<GG, 256, 0, stream>>>(
                nullptr, zbuf, wt0,
                st1p, bn2g + (i - 1) * DD, bn2b + (i - 1) * DD,
                st2p, bn3g + (i - 1) * DD, bn3b + (i - 1) * DD,
                y0buf, nullptr);
        }

        gather_kernel<<<GA, 256, 0, stream>>>(y0buf, off, (const long long*)em, ybuf, st0);

        gemm_mfma<2><<<GG, 256, 0, stream>>>(
            nullptr, ybuf, wt1,
            st0, bn1g + i * DD, bn1b + i * DD,
            nullptr, nullptr, nullptr,
            zbuf, st1);

        stats_relu<<<1024, 256, 0, stream>>>(zbuf, st1, bn2g + i * DD, bn2b + i * DD, st2);
    }

    final_apply<<<2048, 256, 0, stream>>>(
        zbuf,
        stats + (2 * 3 + 1) * SB, bn2g + 2 * DD, bn2b + 2 * DD,
        stats + (2 * 3 + 2) * SB, bn3g + 2 * DD, bn3b + 2 * DD,
        out);
}